// Round 5
// baseline (559.353 us; speedup 1.0000x reference)
//
#include <hip/hip_runtime.h>

#define NE 8          // routed experts
#define HD 1024       // hidden
#define MD 2048       // intermediate
#define NT 2048       // tokens (2*1024)
#define NSH 4224      // shared-expert row base (>= padded routed rows, %16==0)

typedef __attribute__((ext_vector_type(8))) short s16x8;
typedef __attribute__((ext_vector_type(4))) float f32x4;
typedef __attribute__((ext_vector_type(8))) unsigned short u16x8;
typedef __attribute__((ext_vector_type(4))) unsigned short u16x4;

__device__ __forceinline__ unsigned short f2bf(float f) {
    union { float f; unsigned int i; } v; v.f = f;
    unsigned int u = v.i;
    return (unsigned short)((u + 0x7FFFu + ((u >> 16) & 1u)) >> 16);
}
__device__ __forceinline__ float bf2f(unsigned short u) {
    union { unsigned int i; float f; } v; v.i = ((unsigned int)u) << 16; return v.f;
}

// async 16B global -> LDS (HW adds lane*16 to wave-uniform LDS base)
__device__ __forceinline__ void gld16(const unsigned short* g, short* l) {
    __builtin_amdgcn_global_load_lds(
        (const __attribute__((address_space(1))) unsigned int*)g,
        (__attribute__((address_space(3))) unsigned int*)l,
        16, 0, 0);
}

// Blocked bf16 layout for B-operands and h:
//   elem(r, k) at ((r>>4)*(K>>3) + (k>>3))*128 + (r&15)*8 + (k&7)
// A 16-row x 32-k slab is 1KB contiguous = one wave's global_load_lds.

// ---------------- K0b: gate+up fp32 -> interleaved blocked bf16 -----------
__global__ __launch_bounds__(256) void k_cvt_gu(
    const float* __restrict__ wg, const float* __restrict__ wu,
    const float* __restrict__ swg, const float* __restrict__ swu,
    unsigned short* __restrict__ o)
{
    int e = blockIdx.z;
    const float* sg = (e < NE) ? wg + (size_t)e * HD * MD : swg;
    const float* su = (e < NE) ? wu + (size_t)e * HD * MD : swu;
    unsigned short* dst = o + (size_t)e * (2 * MD) * HD;
    int k0 = blockIdx.x * 32, n0 = blockIdx.y * 128;
    __shared__ float T[2 * 32 * 132];   // [mat][k][132]
    int tid = threadIdx.x;
    #pragma unroll
    for (int p = 0; p < 4; p++) {
        int idx = p * 256 + tid;
        int row = idx >> 5, l4 = (idx & 31) * 4;
        float4 vg = *(const float4*)(sg + (size_t)(k0 + row) * MD + n0 + l4);
        float4 vu = *(const float4*)(su + (size_t)(k0 + row) * MD + n0 + l4);
        *(float4*)(&T[row * 132 + l4]) = vg;
        *(float4*)(&T[32 * 132 + row * 132 + l4]) = vu;
    }
    __syncthreads();
    const int KC = HD / 8;   // 128
    #pragma unroll
    for (int p = 0; p < 4; p++) {
        int c = p * 256 + tid;
        int ni = c & 15, ns = (c >> 4) & 15, kc = c >> 8;
        int colL = ns * 8 + (ni >> 1);
        const float* Tm = &T[(ni & 1) * 32 * 132];
        u16x8 r;
        #pragma unroll
        for (int j = 0; j < 8; j++) r[j] = f2bf(Tm[(kc * 8 + j) * 132 + colL]);
        size_t oidx = ((size_t)((n0 >> 3) + ns) * KC + (k0 >> 3) + kc) * 128 + ni * 8;
        *(u16x8*)(dst + oidx) = r;
    }
}

// ---------------- K0c: down fp32 [e][K=MD][N=HD] -> blocked bf16 ----------
__global__ __launch_bounds__(256) void k_cvt_d(
    const float* __restrict__ wr, const float* __restrict__ wsd,
    unsigned short* __restrict__ o)
{
    int e = blockIdx.z;
    const float* src = (e < NE) ? wr + (size_t)e * MD * HD : wsd;
    unsigned short* dst = o + (size_t)e * MD * HD;
    int k0 = blockIdx.x * 32, n0 = blockIdx.y * 128;
    __shared__ float T[32 * 132];
    int tid = threadIdx.x;
    #pragma unroll
    for (int p = 0; p < 4; p++) {
        int idx = p * 256 + tid;
        int row = idx >> 5, l4 = (idx & 31) * 4;
        float4 v = *(const float4*)(src + (size_t)(k0 + row) * HD + n0 + l4);
        *(float4*)(&T[row * 132 + l4]) = v;
    }
    __syncthreads();
    const int KC = MD / 8;   // 256
    #pragma unroll
    for (int p = 0; p < 2; p++) {
        int c = p * 256 + tid;
        int ni = c & 15, ns = (c >> 4) & 7, kc = c >> 7;
        int colL = ns * 16 + ni;
        u16x8 r;
        #pragma unroll
        for (int j = 0; j < 8; j++) r[j] = f2bf(T[(kc * 8 + j) * 132 + colL]);
        size_t oidx = ((size_t)((n0 >> 4) + ns) * KC + (k0 >> 3) + kc) * 128 + ni * 8;
        *(u16x8*)(dst + oidx) = r;
    }
}

// ---------------- K1: routing + x bf16 convert (one wave per token) -------
__global__ __launch_bounds__(256) void k_route(
    const float* __restrict__ x, const float* __restrict__ gw,
    const float* __restrict__ beta,
    int* __restrict__ cnt, int* __restrict__ list, int* __restrict__ slot,
    float* __restrict__ rprob, unsigned short* __restrict__ xb)
{
    int wave = threadIdx.x >> 6, lane = threadIdx.x & 63;
    int t = blockIdx.x * 4 + wave;
    const float4* xp = (const float4*)(x + (size_t)t * HD) + lane * 4;
    float4 xv[4];
    #pragma unroll
    for (int j = 0; j < 4; j++) xv[j] = xp[j];

    u16x8 o0, o1;
    o0[0] = f2bf(xv[0].x); o0[1] = f2bf(xv[0].y); o0[2] = f2bf(xv[0].z); o0[3] = f2bf(xv[0].w);
    o0[4] = f2bf(xv[1].x); o0[5] = f2bf(xv[1].y); o0[6] = f2bf(xv[1].z); o0[7] = f2bf(xv[1].w);
    o1[0] = f2bf(xv[2].x); o1[1] = f2bf(xv[2].y); o1[2] = f2bf(xv[2].z); o1[3] = f2bf(xv[2].w);
    o1[4] = f2bf(xv[3].x); o1[5] = f2bf(xv[3].y); o1[6] = f2bf(xv[3].z); o1[7] = f2bf(xv[3].w);
    *(u16x8*)(xb + (size_t)t * HD + lane * 16) = o0;
    *(u16x8*)(xb + (size_t)t * HD + lane * 16 + 8) = o1;

    float logit[NE];
    #pragma unroll
    for (int e = 0; e < NE; e++) {
        const float4* gp = (const float4*)(gw + e * HD) + lane * 4;
        float s = 0.f;
        #pragma unroll
        for (int j = 0; j < 4; j++) {
            float4 g = gp[j];
            s += xv[j].x * g.x + xv[j].y * g.y + xv[j].z * g.z + xv[j].w * g.w;
        }
        for (int off = 32; off > 0; off >>= 1) s += __shfl_xor(s, off);
        logit[e] = s;
    }
    if (lane == 0) {
        float v[NE];
        #pragma unroll
        for (int e = 0; e < NE; e++) v[e] = logit[e] + beta[e];
        int i1 = 0; float m1 = v[0];
        #pragma unroll
        for (int e = 1; e < NE; e++) if (v[e] > m1) { m1 = v[e]; i1 = e; }
        int i2 = -1; float m2 = -3.4e38f;
        #pragma unroll
        for (int e = 0; e < NE; e++) if (e != i1 && v[e] > m2) { m2 = v[e]; i2 = e; }
        if (i2 < 0) i2 = (i1 + 1) & 7;
        float p1 = 1.f / (1.f + __expf(-logit[i1]));
        float p2 = 1.f / (1.f + __expf(-logit[i2]));
        int pos1 = atomicAdd(cnt + i1, 1);
        list[i1 * NT + pos1] = t; slot[t * 2 + 0] = (i1 << 16) | pos1; rprob[t * 2 + 0] = p1;
        int pos2 = atomicAdd(cnt + i2, 1);
        list[i2 * NT + pos2] = t; slot[t * 2 + 1] = (i2 << 16) | pos2; rprob[t * 2 + 1] = p2;
    }
}

// ---------------- K2: scan + tile tables (128-gran for gateup, 64 for down)
__global__ void k_scan(const int* __restrict__ cnt, int* __restrict__ base,
                       int* __restrict__ tmap, int* __restrict__ ntile,
                       int* __restrict__ tmap2, int* __restrict__ ntile2) {
    if (threadIdx.x == 0) {
        int run = 0, nt = 0, nt2 = 0;
        for (int e = 0; e < NE; e++) {
            base[e] = run;
            int c = cnt[e];
            run += (c + 15) & ~15;
            for (int i0 = 0; i0 < c; i0 += 128) tmap[nt++] = (e << 8) | (i0 >> 7);
            for (int i0 = 0; i0 < c; i0 += 64)  tmap2[nt2++] = (e << 8) | (i0 >> 6);
        }
        base[NE] = run;
        for (int i0 = 0; i0 < NT; i0 += 128) tmap[nt++] = (NE << 8) | (i0 >> 7);
        for (int i0 = 0; i0 < NT; i0 += 64)  tmap2[nt2++] = (NE << 8) | (i0 >> 6);
        *ntile = nt;
        *ntile2 = nt2;
    }
}

// ---------------- K3: gathered gate+up GEMM, LDS-staged h epilogue --------
// h-write fix: 2-byte scattered epilogue stores caused L2 partial-line
// thrash under dense co-residency (WRITE 166MB vs h=24.5MB, r4 counters).
// Stage the 128x64 h-tile in LDS (reusing As, exactly 16KB), then stream
// 8 x 2KB fully-contiguous runs -> full-line writes, no write-allocate.
__global__ __launch_bounds__(256, 5) void k_gateup(
    const unsigned short* __restrict__ x,
    const unsigned short* __restrict__ wgu,
    const int* __restrict__ cnt, const int* __restrict__ base, const int* __restrict__ list,
    const int* __restrict__ tmap, const int* __restrict__ ntile,
    unsigned short* __restrict__ h)
{
    int ti = blockIdx.x >> 5, ntl = blockIdx.x & 31;
    if (ti >= *ntile) return;
    int mv = tmap[ti];
    int e = mv >> 8;
    int i0 = (mv & 255) << 7;
    int n0 = ntl * 128;                       // interleaved col space [0, 2*MD)
    int cnte = (e < NE) ? cnt[e] : NT;
    int rbase = (e < NE) ? base[e] : NSH;
    const unsigned short* wb = wgu + (size_t)e * (2 * MD) * HD;

    __shared__ short As[2][128 * 32];         // 16 KB (reused as h staging)
    __shared__ short Bs[2][8 * 512];          // 16 KB -> total 32 KB = 5 blk/CU

    int tid = threadIdx.x;
    int lane = tid & 63, wave = tid >> 6;

    int rr = wave * 32 + (lane >> 2);
    int gi0r = i0 + rr, gi1r = i0 + rr + 16;
    int t0, t1;
    if (e < NE) {
        t0 = list[e * NT + (gi0r < cnte ? gi0r : cnte - 1)];
        t1 = list[e * NT + (gi1r < cnte ? gi1r : cnte - 1)];
    } else { t0 = gi0r; t1 = gi1r; }

    int kc = ((lane & 3) ^ ((lane >> 3) & 3)) * 8;   // A source chunk swizzle
    size_t gaA0 = (size_t)t0 * HD + kc;
    size_t gaA1 = (size_t)t1 * HD + kc;
    const int KC = HD / 8;   // 128
    size_t gaB0 = ((size_t)((n0 >> 4) + 2 * wave) * KC) * 128 + lane * 8;
    size_t gaB1 = gaB0 + (size_t)KC * 128;
    int loA0 = (wave * 32) * 32, loA1 = (wave * 32 + 16) * 32;
    int loB0 = (2 * wave) * 512, loB1 = (2 * wave + 1) * 512;

    int wr = (wave >> 1) * 64, wc = (wave & 1) * 64;
    int m = lane & 15, q = lane >> 4;
    int sa = (m >> 1) & 3;                  // A read-side swizzle (yields true chunk q)

    f32x4 acc[4][4];
    #pragma unroll
    for (int a = 0; a < 4; a++)
        #pragma unroll
        for (int b = 0; b < 4; b++) acc[a][b] = (f32x4)0.f;

    gld16(x + gaA0, &As[0][loA0]);
    gld16(x + gaA1, &As[0][loA1]);
    gld16(wb + gaB0, &Bs[0][loB0]);
    gld16(wb + gaB1, &Bs[0][loB1]);

    int it = 0;
    for (int k0 = 0; k0 < HD; k0 += 32, it ^= 1) {
        __syncthreads();   // drains this buf's prefetch (issued one iter ago)
        int nk = k0 + 32;
        if (nk < HD) {
            int nb = it ^ 1;
            gld16(x + gaA0 + nk, &As[nb][loA0]);
            gld16(x + gaA1 + nk, &As[nb][loA1]);
            gld16(wb + gaB0 + (size_t)nk * 16, &Bs[nb][loB0]);
            gld16(wb + gaB1 + (size_t)nk * 16, &Bs[nb][loB1]);
        }
        s16x8 af[4];
        #pragma unroll
        for (int ti2 = 0; ti2 < 4; ti2++)
            af[ti2] = *(const s16x8*)(&As[it][(wr + ti2 * 16 + m) * 32 + (q ^ sa) * 8]);
        #pragma unroll
        for (int tj = 0; tj < 4; tj++) {
            s16x8 bf = *(const s16x8*)(&Bs[it][((wave & 1) * 4 + tj) * 512 + q * 128 + m * 8]);
            #pragma unroll
            for (int ti2 = 0; ti2 < 4; ti2++)
                acc[ti2][tj] = __builtin_amdgcn_mfma_f32_16x16x32_bf16(af[ti2], bf, acc[ti2][tj], 0, 0, 0);
        }
    }
    // ---- staged epilogue: silu pair -> LDS tile -> contiguous stream-out
    __syncthreads();                          // all waves done reading As/Bs
    short* st = (short*)As;                   // 8192 shorts = 128x64 blocked tile
    #pragma unroll
    for (int ti2 = 0; ti2 < 4; ti2++)
        #pragma unroll
        for (int tj = 0; tj < 4; tj++)
            #pragma unroll
            for (int r = 0; r < 4; r++) {
                float v = acc[ti2][tj][r];
                float uo = __shfl_xor(v, 1);
                if (!(m & 1)) {
                    int row = wr + ti2 * 16 + q * 4 + r;            // 0..127
                    int hcol = (wc + tj * 16 + m) >> 1;             // 0..63
                    float g = v;
                    float hv = (g / (1.f + __expf(-g))) * uo;
                    st[((row >> 4) * 8 + (hcol >> 3)) * 128 + (row & 15) * 8 + (hcol & 7)]
                        = (short)f2bf(hv);
                }
            }
    __syncthreads();
    int pad = (cnte + 15) & ~15;              // expert's padded row bound
    int s = tid >> 5;                         // slab-row 0..7 (rows i0+16s..)
    int o = (tid & 31) * 32;
    if (16 * s < pad - i0) {
        size_t gb = ((size_t)((rbase + i0) >> 4) + s) * (MD >> 3) * 128
                  + (size_t)(n0 >> 4) * 128;
        #pragma unroll
        for (int j = 0; j < 4; j++)
            *(u16x8*)(h + gb + o + j * 8) = *(const u16x8*)(&st[s * 1024 + o + j * 8]);
    }
}

// ---------------- K4: down projection, 64-row tiles (896 blocks, 6/CU) ----
__global__ __launch_bounds__(256, 6) void k_down(
    const unsigned short* __restrict__ wd_all,
    const int* __restrict__ cnt, const int* __restrict__ base,
    const int* __restrict__ tmap2, const int* __restrict__ ntile2,
    const unsigned short* __restrict__ h, unsigned short* __restrict__ eo)
{
    int ti = blockIdx.x >> 3, ntl = blockIdx.x & 7;
    if (ti >= *ntile2) return;
    int mv = tmap2[ti];
    int e = mv >> 8;
    int i0 = (mv & 255) << 6;                 // 64-row granularity
    int n0 = ntl * 128;
    int cnte = (e < NE) ? cnt[e] : NT;
    int rbase = (e < NE) ? base[e] : NSH;
    const unsigned short* wd = wd_all + (size_t)e * MD * HD;

    __shared__ short SH[12288];               // As[2][2048] | Bd[2][4096] = 24 KB

    int tid = threadIdx.x;
    int lane = tid & 63, wave = tid >> 6;
    int r0 = rbase + i0;                      // 16-aligned (padded bases)
    const int KC = MD / 8;   // 256
    size_t gaA  = ((size_t)((r0 >> 4) + wave) * KC) * 128 + lane * 8;     // 1 A slab/wave
    size_t gaB0 = ((size_t)((n0 >> 4) + 2 * wave) * KC) * 128 + lane * 8;
    size_t gaB1 = gaB0 + (size_t)KC * 128;
    int loA = wave * 512;
    int loB0 = (2 * wave) * 512, loB1 = loB0 + 512;

    int m = lane & 15, q = lane >> 4;

    f32x4 acc[4][2];
    #pragma unroll
    for (int a = 0; a < 4; a++)
        #pragma unroll
        for (int b = 0; b < 2; b++) acc[a][b] = (f32x4)0.f;

    gld16(h + gaA, SH + loA);
    gld16(wd + gaB0, SH + 4096 + loB0);
    gld16(wd + gaB1, SH + 4096 + loB1);

    int it = 0;
    for (int k0 = 0; k0 < MD; k0 += 32, it ^= 1) {
        __syncthreads();
        int nk = k0 + 32;
        if (nk < MD) {
            int nb = it ^ 1;
            gld16(h + gaA + (size_t)nk * 16, SH + nb * 2048 + loA);
            gld16(wd + gaB0 + (size_t)nk * 16, SH + 4096 + nb * 4096 + loB0);
            gld16(wd + gaB1 + (size_t)nk * 16, SH + 4096 + nb * 4096 + loB1);
        }
        s16x8 af[4];
        #pragma unroll
        for (int ti2 = 0; ti2 < 4; ti2++)
            af[ti2] = *(const s16x8*)(&SH[it * 2048 + ti2 * 512 + q * 128 + m * 8]);
        #pragma unroll
        for (int tj = 0; tj < 2; tj++) {
            s16x8 bd = *(const s16x8*)(&SH[4096 + it * 4096 + (wave * 2 + tj) * 512 + q * 128 + m * 8]);
            #pragma unroll
            for (int ti2 = 0; ti2 < 4; ti2++)
                acc[ti2][tj] = __builtin_amdgcn_mfma_f32_16x16x32_bf16(af[ti2], bd, acc[ti2][tj], 0, 0, 0);
        }
    }
    #pragma unroll
    for (int ti2 = 0; ti2 < 4; ti2++)
        #pragma unroll
        for (int tj = 0; tj < 2; tj++)
            #pragma unroll
            for (int r = 0; r < 4; r++) {
                int gi = i0 + ti2 * 16 + q * 4 + r;
                if (gi < cnte) {
                    int col = n0 + wave * 32 + tj * 16 + m;
                    eo[(size_t)(rbase + gi) * HD + col] = f2bf(acc[ti2][tj][r]);
                }
            }
}

// ---------------- K5: weighted combine -> fp32 out ----------------
__global__ __launch_bounds__(256) void k_combine(
    const unsigned short* __restrict__ eo, const int* __restrict__ slot,
    const float* __restrict__ rprob, const int* __restrict__ base,
    float* __restrict__ out)
{
    int t = blockIdx.x;
    int s0 = slot[t * 2], s1 = slot[t * 2 + 1];
    float p0 = rprob[t * 2], p1 = rprob[t * 2 + 1];
    int r0 = base[s0 >> 16] + (s0 & 0xFFFF);
    int r1 = base[s1 >> 16] + (s1 & 0xFFFF);
    int rs = NSH + t;
    int c = threadIdx.x * 4;
    u16x4 a = *(const u16x4*)(eo + (size_t)r0 * HD + c);
    u16x4 b = *(const u16x4*)(eo + (size_t)r1 * HD + c);
    u16x4 s = *(const u16x4*)(eo + (size_t)rs * HD + c);
    float4 res;
    res.x = p0 * bf2f(a[0]) + p1 * bf2f(b[0]) + bf2f(s[0]);
    res.y = p0 * bf2f(a[1]) + p1 * bf2f(b[1]) + bf2f(s[1]);
    res.z = p0 * bf2f(a[2]) + p1 * bf2f(b[2]) + bf2f(s[2]);
    res.w = p0 * bf2f(a[3]) + p1 * bf2f(b[3]) + bf2f(s[3]);
    *(float4*)(out + (size_t)t * HD + c) = res;
}

extern "C" void kernel_launch(void* const* d_in, const int* in_sizes, int n_in,
                              void* d_out, int out_size, void* d_ws, size_t ws_size,
                              hipStream_t stream)
{
    const float* x    = (const float*)d_in[0];
    const float* gw   = (const float*)d_in[1];
    const float* beta = (const float*)d_in[2];
    const float* wg   = (const float*)d_in[3];
    const float* wu   = (const float*)d_in[4];
    const float* wd   = (const float*)d_in[5];
    const float* swg  = (const float*)d_in[6];
    const float* swu  = (const float*)d_in[7];
    const float* swd  = (const float*)d_in[8];
    float* out = (float*)d_out;

    char* ws = (char*)d_ws;
    const size_t MB = (size_t)1 << 20;
    int*   cnt    = (int*)(ws + 0);
    int*   basep  = (int*)(ws + 64);
    int*   ntile  = (int*)(ws + 128);
    int*   ntile2 = (int*)(ws + 132);
    int*   tmap   = (int*)(ws + 192);    // <=56 entries
    int*   tmap2  = (int*)(ws + 512);    // <=104 entries
    int*   list   = (int*)(ws + 1024);
    int*   slot   = (int*)(ws + 1024 + 65536);
    float* rprob  = (float*)(ws + 1024 + 65536 + 16384);
    unsigned short* xb   = (unsigned short*)(ws + 1 * MB);    // [2048][1024]
    unsigned short* eo   = (unsigned short*)(ws + 6 * MB);    // [6272][1024]
    unsigned short* wgut = (unsigned short*)(ws + 20 * MB);   // [9] blocked interleaved [4096 x 1024]
    unsigned short* wdt  = (unsigned short*)(ws + 92 * MB);   // [9] blocked [1024 x 2048]
    unsigned short* h    = (unsigned short*)(ws + 128 * MB);  // [6272 x 2048] blocked

    hipMemsetAsync(ws, 0, 128, stream);

    dim3 tgu(HD / 32, MD / 128, NE + 1);
    k_cvt_gu<<<tgu, 256, 0, stream>>>(wg, wu, swg, swu, wgut);
    dim3 td(MD / 32, HD / 128, NE + 1);
    k_cvt_d<<<td, 256, 0, stream>>>(wd, swd, wdt);

    k_route<<<NT / 4, 256, 0, stream>>>(x, gw, beta, cnt, list, slot, rprob, xb);
    k_scan<<<1, 64, 0, stream>>>(cnt, basep, tmap, ntile, tmap2, ntile2);

    k_gateup<<<1792, 256, 0, stream>>>(xb, wgut, cnt, basep, list, tmap, ntile, h);

    k_down<<<896, 256, 0, stream>>>(wdt, cnt, basep, tmap2, ntile2, h, eo);

    k_combine<<<NT, 256, 0, stream>>>(eo, slot, rprob, basep, out);
}

// Round 6
// 440.011 us; speedup vs baseline: 1.2712x; 1.2712x over previous
//
#include <hip/hip_runtime.h>

#define NE 8          // routed experts
#define HD 1024       // hidden
#define MD 2048       // intermediate
#define NT 2048       // tokens (2*1024)
#define NSH 4224      // shared-expert row base (>= padded routed rows, %16==0)

typedef __attribute__((ext_vector_type(8))) short s16x8;
typedef __attribute__((ext_vector_type(4))) float f32x4;
typedef __attribute__((ext_vector_type(8))) unsigned short u16x8;
typedef __attribute__((ext_vector_type(4))) unsigned short u16x4;

__device__ __forceinline__ unsigned short f2bf(float f) {
    union { float f; unsigned int i; } v; v.f = f;
    unsigned int u = v.i;
    return (unsigned short)((u + 0x7FFFu + ((u >> 16) & 1u)) >> 16);
}
__device__ __forceinline__ float bf2f(unsigned short u) {
    union { unsigned int i; float f; } v; v.i = ((unsigned int)u) << 16; return v.f;
}

// async 16B global -> LDS (HW adds lane*16 to wave-uniform LDS base)
__device__ __forceinline__ void gld16(const unsigned short* g, short* l) {
    __builtin_amdgcn_global_load_lds(
        (const __attribute__((address_space(1))) unsigned int*)g,
        (__attribute__((address_space(3))) unsigned int*)l,
        16, 0, 0);
}

// Blocked bf16 layout for B-operands and h:
//   elem(r, k) at ((r>>4)*(K>>3) + (k>>3))*128 + (r&15)*8 + (k&7)
// A 16-row x 32-k slab is 1KB contiguous = one wave's global_load_lds.

// ---------------- K0b: gate+up fp32 -> interleaved blocked bf16 -----------
// (retiled R3 version: 512B-run reads; independent of the GEMM regression)
__global__ __launch_bounds__(256) void k_cvt_gu(
    const float* __restrict__ wg, const float* __restrict__ wu,
    const float* __restrict__ swg, const float* __restrict__ swu,
    unsigned short* __restrict__ o)
{
    int e = blockIdx.z;
    const float* sg = (e < NE) ? wg + (size_t)e * HD * MD : swg;
    const float* su = (e < NE) ? wu + (size_t)e * HD * MD : swu;
    unsigned short* dst = o + (size_t)e * (2 * MD) * HD;
    int k0 = blockIdx.x * 32, n0 = blockIdx.y * 128;
    __shared__ float T[2 * 32 * 132];   // [mat][k][132]
    int tid = threadIdx.x;
    #pragma unroll
    for (int p = 0; p < 4; p++) {
        int idx = p * 256 + tid;
        int row = idx >> 5, l4 = (idx & 31) * 4;
        float4 vg = *(const float4*)(sg + (size_t)(k0 + row) * MD + n0 + l4);
        float4 vu = *(const float4*)(su + (size_t)(k0 + row) * MD + n0 + l4);
        *(float4*)(&T[row * 132 + l4]) = vg;
        *(float4*)(&T[32 * 132 + row * 132 + l4]) = vu;
    }
    __syncthreads();
    const int KC = HD / 8;   // 128
    #pragma unroll
    for (int p = 0; p < 4; p++) {
        int c = p * 256 + tid;
        int ni = c & 15, ns = (c >> 4) & 15, kc = c >> 8;
        int colL = ns * 8 + (ni >> 1);
        const float* Tm = &T[(ni & 1) * 32 * 132];
        u16x8 r;
        #pragma unroll
        for (int j = 0; j < 8; j++) r[j] = f2bf(Tm[(kc * 8 + j) * 132 + colL]);
        size_t oidx = ((size_t)((n0 >> 3) + ns) * KC + (k0 >> 3) + kc) * 128 + ni * 8;
        *(u16x8*)(dst + oidx) = r;
    }
}

// ---------------- K0c: down fp32 [e][K=MD][N=HD] -> blocked bf16 ----------
__global__ __launch_bounds__(256) void k_cvt_d(
    const float* __restrict__ wr, const float* __restrict__ wsd,
    unsigned short* __restrict__ o)
{
    int e = blockIdx.z;
    const float* src = (e < NE) ? wr + (size_t)e * MD * HD : wsd;
    unsigned short* dst = o + (size_t)e * MD * HD;
    int k0 = blockIdx.x * 32, n0 = blockIdx.y * 128;
    __shared__ float T[32 * 132];
    int tid = threadIdx.x;
    #pragma unroll
    for (int p = 0; p < 4; p++) {
        int idx = p * 256 + tid;
        int row = idx >> 5, l4 = (idx & 31) * 4;
        float4 v = *(const float4*)(src + (size_t)(k0 + row) * HD + n0 + l4);
        *(float4*)(&T[row * 132 + l4]) = v;
    }
    __syncthreads();
    const int KC = MD / 8;   // 256
    #pragma unroll
    for (int p = 0; p < 2; p++) {
        int c = p * 256 + tid;
        int ni = c & 15, ns = (c >> 4) & 7, kc = c >> 7;
        int colL = ns * 16 + ni;
        u16x8 r;
        #pragma unroll
        for (int j = 0; j < 8; j++) r[j] = f2bf(T[(kc * 8 + j) * 132 + colL]);
        size_t oidx = ((size_t)((n0 >> 4) + ns) * KC + (k0 >> 3) + kc) * 128 + ni * 8;
        *(u16x8*)(dst + oidx) = r;
    }
}

// ---------------- K1: routing + x bf16 convert (one wave per token) -------
__global__ __launch_bounds__(256) void k_route(
    const float* __restrict__ x, const float* __restrict__ gw,
    const float* __restrict__ beta,
    int* __restrict__ cnt, int* __restrict__ list, int* __restrict__ slot,
    float* __restrict__ rprob, unsigned short* __restrict__ xb)
{
    int wave = threadIdx.x >> 6, lane = threadIdx.x & 63;
    int t = blockIdx.x * 4 + wave;
    const float4* xp = (const float4*)(x + (size_t)t * HD) + lane * 4;
    float4 xv[4];
    #pragma unroll
    for (int j = 0; j < 4; j++) xv[j] = xp[j];

    u16x8 o0, o1;
    o0[0] = f2bf(xv[0].x); o0[1] = f2bf(xv[0].y); o0[2] = f2bf(xv[0].z); o0[3] = f2bf(xv[0].w);
    o0[4] = f2bf(xv[1].x); o0[5] = f2bf(xv[1].y); o0[6] = f2bf(xv[1].z); o0[7] = f2bf(xv[1].w);
    o1[0] = f2bf(xv[2].x); o1[1] = f2bf(xv[2].y); o1[2] = f2bf(xv[2].z); o1[3] = f2bf(xv[2].w);
    o1[4] = f2bf(xv[3].x); o1[5] = f2bf(xv[3].y); o1[6] = f2bf(xv[3].z); o1[7] = f2bf(xv[3].w);
    *(u16x8*)(xb + (size_t)t * HD + lane * 16) = o0;
    *(u16x8*)(xb + (size_t)t * HD + lane * 16 + 8) = o1;

    float logit[NE];
    #pragma unroll
    for (int e = 0; e < NE; e++) {
        const float4* gp = (const float4*)(gw + e * HD) + lane * 4;
        float s = 0.f;
        #pragma unroll
        for (int j = 0; j < 4; j++) {
            float4 g = gp[j];
            s += xv[j].x * g.x + xv[j].y * g.y + xv[j].z * g.z + xv[j].w * g.w;
        }
        for (int off = 32; off > 0; off >>= 1) s += __shfl_xor(s, off);
        logit[e] = s;
    }
    if (lane == 0) {
        float v[NE];
        #pragma unroll
        for (int e = 0; e < NE; e++) v[e] = logit[e] + beta[e];
        int i1 = 0; float m1 = v[0];
        #pragma unroll
        for (int e = 1; e < NE; e++) if (v[e] > m1) { m1 = v[e]; i1 = e; }
        int i2 = -1; float m2 = -3.4e38f;
        #pragma unroll
        for (int e = 0; e < NE; e++) if (e != i1 && v[e] > m2) { m2 = v[e]; i2 = e; }
        if (i2 < 0) i2 = (i1 + 1) & 7;
        float p1 = 1.f / (1.f + __expf(-logit[i1]));
        float p2 = 1.f / (1.f + __expf(-logit[i2]));
        int pos1 = atomicAdd(cnt + i1, 1);
        list[i1 * NT + pos1] = t; slot[t * 2 + 0] = (i1 << 16) | pos1; rprob[t * 2 + 0] = p1;
        int pos2 = atomicAdd(cnt + i2, 1);
        list[i2 * NT + pos2] = t; slot[t * 2 + 1] = (i2 << 16) | pos2; rprob[t * 2 + 1] = p2;
    }
}

// ---------------- K2: tiny scan for row bases (16-aligned for slabs) ------
__global__ void k_scan(const int* __restrict__ cnt, int* __restrict__ base) {
    if (threadIdx.x == 0) {
        int run = 0;
        for (int e = 0; e < NE; e++) { base[e] = run; run += (cnt[e] + 15) & ~15; }
        base[NE] = run;
    }
}

// ---------------- K3: gathered gate+up GEMM (verbatim round-2 config) -----
// 3D sparse grid + tok LDS + 4 blk/CU + direct scattered h stores:
// the only configuration with verified-good counters (87us, F74/W24.6).
__global__ __launch_bounds__(256, 4) void k_gateup(
    const unsigned short* __restrict__ x,
    const unsigned short* __restrict__ wgu,
    const int* __restrict__ cnt, const int* __restrict__ base, const int* __restrict__ list,
    unsigned short* __restrict__ h)
{
    int e = blockIdx.z;
    int i0 = blockIdx.y * 128;
    int n0 = blockIdx.x * 128;              // interleaved col space [0, 2*MD)
    int cnte = (e < NE) ? cnt[e] : NT;
    if (i0 >= cnte) return;
    int rbase = (e < NE) ? base[e] : NSH;
    const unsigned short* wb = wgu + (size_t)e * (2 * MD) * HD;

    __shared__ short As[2][128 * 32];
    __shared__ short Bs[2][8 * 512];        // 8 slabs of [4 chunk][16 ni][8 k]
    __shared__ int tok[128];

    int tid = threadIdx.x;
    int lane = tid & 63, wave = tid >> 6;
    if (tid < 128) {
        int gi = i0 + tid;
        tok[tid] = (e < NE) ? ((gi < cnte) ? list[e * NT + gi] : list[e * NT]) : gi;
    }
    __syncthreads();

    int rr = wave * 32 + (lane >> 2);
    int kc = ((lane & 3) ^ ((lane >> 3) & 3)) * 8;   // A source chunk swizzle
    size_t gaA0 = (size_t)tok[rr] * HD + kc;
    size_t gaA1 = (size_t)tok[rr + 16] * HD + kc;
    const int KC = HD / 8;   // 128
    size_t gaB0 = ((size_t)((n0 >> 4) + 2 * wave) * KC) * 128 + lane * 8;
    size_t gaB1 = gaB0 + (size_t)KC * 128;
    int loA0 = (wave * 32) * 32, loA1 = (wave * 32 + 16) * 32;
    int loB0 = (2 * wave) * 512, loB1 = (2 * wave + 1) * 512;

    int wr = (wave >> 1) * 64, wc = (wave & 1) * 64;
    int m = lane & 15, q = lane >> 4;
    int sa = (m >> 1) & 3;                  // A read-side swizzle (yields true chunk q)

    f32x4 acc[4][4];
    #pragma unroll
    for (int a = 0; a < 4; a++)
        #pragma unroll
        for (int b = 0; b < 4; b++) acc[a][b] = (f32x4)0.f;

    gld16(x + gaA0, &As[0][loA0]);
    gld16(x + gaA1, &As[0][loA1]);
    gld16(wb + gaB0, &Bs[0][loB0]);
    gld16(wb + gaB1, &Bs[0][loB1]);

    int it = 0;
    for (int k0 = 0; k0 < HD; k0 += 32, it ^= 1) {
        __syncthreads();   // drains this buf's prefetch (issued one iter ago)
        int nk = k0 + 32;
        if (nk < HD) {
            int nb = it ^ 1;
            gld16(x + gaA0 + nk, &As[nb][loA0]);
            gld16(x + gaA1 + nk, &As[nb][loA1]);
            gld16(wb + gaB0 + (size_t)nk * 16, &Bs[nb][loB0]);
            gld16(wb + gaB1 + (size_t)nk * 16, &Bs[nb][loB1]);
        }
        s16x8 af[4];
        #pragma unroll
        for (int ti2 = 0; ti2 < 4; ti2++)
            af[ti2] = *(const s16x8*)(&As[it][(wr + ti2 * 16 + m) * 32 + (q ^ sa) * 8]);
        #pragma unroll
        for (int tj = 0; tj < 4; tj++) {
            s16x8 bf = *(const s16x8*)(&Bs[it][((wave & 1) * 4 + tj) * 512 + q * 128 + m * 8]);
            #pragma unroll
            for (int ti2 = 0; ti2 < 4; ti2++)
                acc[ti2][tj] = __builtin_amdgcn_mfma_f32_16x16x32_bf16(af[ti2], bf, acc[ti2][tj], 0, 0, 0);
        }
    }
    // epilogue: pair gate/up across adjacent lanes; even lanes write silu(g)*u
    #pragma unroll
    for (int ti2 = 0; ti2 < 4; ti2++)
        #pragma unroll
        for (int tj = 0; tj < 4; tj++)
            #pragma unroll
            for (int r = 0; r < 4; r++) {
                float v = acc[ti2][tj][r];
                float uo = __shfl_xor(v, 1);
                int gi = i0 + wr + ti2 * 16 + q * 4 + r;
                if (!(m & 1) && gi < cnte) {
                    float g = v;
                    float hv = (g / (1.f + __expf(-g))) * uo;
                    int col = (n0 + wc + tj * 16 + m) >> 1;
                    int rw = rbase + gi;
                    size_t hi = ((size_t)(rw >> 4) * (MD >> 3) + (col >> 3)) * 128
                              + (rw & 15) * 8 + (col & 7);
                    h[hi] = f2bf(hv);
                }
            }
}

// ---------------- K4: down projection (verbatim round-2 config) -----------
__global__ __launch_bounds__(256, 4) void k_down(
    const unsigned short* __restrict__ wd_all,
    const int* __restrict__ cnt, const int* __restrict__ base,
    const unsigned short* __restrict__ h, unsigned short* __restrict__ eo)
{
    int e = blockIdx.z;
    int i0 = blockIdx.y * 128;
    int n0 = blockIdx.x * 128;
    int cnte = (e < NE) ? cnt[e] : NT;
    if (i0 >= cnte) return;
    int rbase = (e < NE) ? base[e] : NSH;
    const unsigned short* wd = wd_all + (size_t)e * MD * HD;

    __shared__ short As[2][8 * 512];
    __shared__ short Bd[2][8 * 512];

    int tid = threadIdx.x;
    int lane = tid & 63, wave = tid >> 6;
    int r0 = rbase + i0;                    // 16-aligned (padded bases)
    const int KC = MD / 8;   // 256
    size_t gaA0 = ((size_t)((r0 >> 4) + 2 * wave) * KC) * 128 + lane * 8;
    size_t gaA1 = gaA0 + (size_t)KC * 128;
    size_t gaB0 = ((size_t)((n0 >> 4) + 2 * wave) * KC) * 128 + lane * 8;
    size_t gaB1 = gaB0 + (size_t)KC * 128;
    int lo0 = (2 * wave) * 512, lo1 = (2 * wave + 1) * 512;

    int wr = (wave >> 1) * 64, wc = (wave & 1) * 64;
    int m = lane & 15, q = lane >> 4;

    f32x4 acc[4][4];
    #pragma unroll
    for (int a = 0; a < 4; a++)
        #pragma unroll
        for (int b = 0; b < 4; b++) acc[a][b] = (f32x4)0.f;

    gld16(h + gaA0, &As[0][lo0]);
    gld16(h + gaA1, &As[0][lo1]);
    gld16(wd + gaB0, &Bd[0][lo0]);
    gld16(wd + gaB1, &Bd[0][lo1]);

    int it = 0;
    for (int k0 = 0; k0 < MD; k0 += 32, it ^= 1) {
        __syncthreads();
        int nk = k0 + 32;
        if (nk < MD) {
            int nb = it ^ 1;
            gld16(h + gaA0 + (size_t)nk * 16, &As[nb][lo0]);
            gld16(h + gaA1 + (size_t)nk * 16, &As[nb][lo1]);
            gld16(wd + gaB0 + (size_t)nk * 16, &Bd[nb][lo0]);
            gld16(wd + gaB1 + (size_t)nk * 16, &Bd[nb][lo1]);
        }
        s16x8 af[4];
        #pragma unroll
        for (int ti2 = 0; ti2 < 4; ti2++)
            af[ti2] = *(const s16x8*)(&As[it][((wave >> 1) * 4 + ti2) * 512 + q * 128 + m * 8]);
        #pragma unroll
        for (int tj = 0; tj < 4; tj++) {
            s16x8 bd = *(const s16x8*)(&Bd[it][((wave & 1) * 4 + tj) * 512 + q * 128 + m * 8]);
            #pragma unroll
            for (int ti2 = 0; ti2 < 4; ti2++)
                acc[ti2][tj] = __builtin_amdgcn_mfma_f32_16x16x32_bf16(af[ti2], bd, acc[ti2][tj], 0, 0, 0);
        }
    }
    #pragma unroll
    for (int ti2 = 0; ti2 < 4; ti2++)
        #pragma unroll
        for (int tj = 0; tj < 4; tj++)
            #pragma unroll
            for (int r = 0; r < 4; r++) {
                int gi = i0 + wr + ti2 * 16 + q * 4 + r;
                if (gi < cnte) {
                    int col = n0 + wc + tj * 16 + m;
                    eo[(size_t)(rbase + gi) * HD + col] = f2bf(acc[ti2][tj][r]);
                }
            }
}

// ---------------- K5: weighted combine -> fp32 out ----------------
__global__ __launch_bounds__(256) void k_combine(
    const unsigned short* __restrict__ eo, const int* __restrict__ slot,
    const float* __restrict__ rprob, const int* __restrict__ base,
    float* __restrict__ out)
{
    int t = blockIdx.x;
    int s0 = slot[t * 2], s1 = slot[t * 2 + 1];
    float p0 = rprob[t * 2], p1 = rprob[t * 2 + 1];
    int r0 = base[s0 >> 16] + (s0 & 0xFFFF);
    int r1 = base[s1 >> 16] + (s1 & 0xFFFF);
    int rs = NSH + t;
    int c = threadIdx.x * 4;
    u16x4 a = *(const u16x4*)(eo + (size_t)r0 * HD + c);
    u16x4 b = *(const u16x4*)(eo + (size_t)r1 * HD + c);
    u16x4 s = *(const u16x4*)(eo + (size_t)rs * HD + c);
    float4 res;
    res.x = p0 * bf2f(a[0]) + p1 * bf2f(b[0]) + bf2f(s[0]);
    res.y = p0 * bf2f(a[1]) + p1 * bf2f(b[1]) + bf2f(s[1]);
    res.z = p0 * bf2f(a[2]) + p1 * bf2f(b[2]) + bf2f(s[2]);
    res.w = p0 * bf2f(a[3]) + p1 * bf2f(b[3]) + bf2f(s[3]);
    *(float4*)(out + (size_t)t * HD + c) = res;
}

extern "C" void kernel_launch(void* const* d_in, const int* in_sizes, int n_in,
                              void* d_out, int out_size, void* d_ws, size_t ws_size,
                              hipStream_t stream)
{
    const float* x    = (const float*)d_in[0];
    const float* gw   = (const float*)d_in[1];
    const float* beta = (const float*)d_in[2];
    const float* wg   = (const float*)d_in[3];
    const float* wu   = (const float*)d_in[4];
    const float* wd   = (const float*)d_in[5];
    const float* swg  = (const float*)d_in[6];
    const float* swu  = (const float*)d_in[7];
    const float* swd  = (const float*)d_in[8];
    float* out = (float*)d_out;

    char* ws = (char*)d_ws;
    const size_t MB = (size_t)1 << 20;
    int*   cnt   = (int*)(ws + 0);
    int*   basep = (int*)(ws + 64);
    int*   list  = (int*)(ws + 1024);
    int*   slot  = (int*)(ws + 1024 + 65536);
    float* rprob = (float*)(ws + 1024 + 65536 + 16384);
    unsigned short* xb   = (unsigned short*)(ws + 1 * MB);    // [2048][1024]
    unsigned short* eo   = (unsigned short*)(ws + 6 * MB);    // [6272][1024]
    unsigned short* wgut = (unsigned short*)(ws + 20 * MB);   // [9] blocked interleaved [4096 x 1024]
    unsigned short* wdt  = (unsigned short*)(ws + 92 * MB);   // [9] blocked [1024 x 2048]
    unsigned short* h    = (unsigned short*)(ws + 128 * MB);  // [6272 x 2048] blocked

    hipMemsetAsync(ws, 0, 128, stream);

    dim3 tgu(HD / 32, MD / 128, NE + 1);
    k_cvt_gu<<<tgu, 256, 0, stream>>>(wg, wu, swg, swu, wgut);
    dim3 td(MD / 32, HD / 128, NE + 1);
    k_cvt_d<<<td, 256, 0, stream>>>(wd, swd, wdt);

    k_route<<<NT / 4, 256, 0, stream>>>(x, gw, beta, cnt, list, slot, rprob, xb);
    k_scan<<<1, 64, 0, stream>>>(cnt, basep);

    dim3 g3(2 * MD / 128, NT / 128, NE + 1);
    k_gateup<<<g3, 256, 0, stream>>>(xb, wgut, cnt, basep, list, h);

    dim3 g4(HD / 128, NT / 128, NE + 1);
    k_down<<<g4, 256, 0, stream>>>(wdt, cnt, basep, h, eo);

    k_combine<<<NT, 256, 0, stream>>>(eo, slot, rprob, basep, out);
}